// Round 13
// baseline (126.451 us; speedup 1.0000x reference)
//
#include <hip/hip_runtime.h>
#include <hip/hip_bf16.h>
#include <float.h>

#define NS 131072
#define DD 64
#define KK 256
#define CPAD 72      // center image row stride in bf16 (144 B, 16B-aligned)
#define NSTAT 16896  // 256 * 66  (cols 0..63 sums | 64 cnt | 65 ssq)
#define XTS 264      // xT row stride in bf16 (528B rows, 16B-aligned)
#define XTSW 132     // XTS/2 dwords
#define NCOPY 512
#define RGROUPS 16
#define RPER 32      // NCOPY / RGROUPS
// ws layout:
//   [0, NCOPY*NSTAT) as ushort bf16   : per-block stat partials (17.3 MB)
//   SCR_OFF_F  + [0, RGROUPS*NSTAT)   : f32 stage-1 scratch
//   P_OFF_F    + [0, 9216)            : bf16 center image [256][72] (36864 B)
//   P_OFF_F    + 9216 + [0,256)       : f32 csq
#define SCR_OFF_F ((size_t)NCOPY * NSTAT / 2)
#define P_OFF_F   (SCR_OFF_F + (size_t)RGROUPS * NSTAT)
#define P_CSQ_F 9216
#define P_IMG_I4 2304
#define P_HALF_I4 1152   // int4 count of one 128-center half

typedef __attribute__((ext_vector_type(8))) short bf16x8;
typedef __attribute__((ext_vector_type(4))) float f32x4;
typedef __attribute__((ext_vector_type(4))) unsigned int u32x4;

// d_out layout (float32 values):
//   [0, NS) assignments | [NS,2NS) min_dists | stats: cnt[256] | sums[256*64] | ssq[256]

__global__ void zero_buf(float* __restrict__ p, int n) {
    int i = blockIdx.x * 256 + threadIdx.x;
    if (i < n) p[i] = 0.f;
}

__device__ inline unsigned short f2bf(float f) {
    union { __hip_bfloat16 h; unsigned short u; } v;
    v.h = __float2bfloat16(f);          // RNE
    return v.u;
}
__device__ inline float bf2f(unsigned short b) {
    return __uint_as_float(((unsigned)b) << 16);
}

// ---------------- K0: prep centers (bf16 image + pads + csq) ----------------
__global__ void prep_centers(const float* __restrict__ ctr, float* __restrict__ P) {
    __shared__ float s_part[32][9];
    const int t = threadIdx.x;
    const int rl = t >> 3, seg = t & 7;
    const int r = blockIdx.x * 32 + rl;
    const float* rp = ctr + r * DD + seg * 8;
    float4 a = ((const float4*)rp)[0];
    float4 b = ((const float4*)rp)[1];
    unsigned short u0 = f2bf(a.x), u1 = f2bf(a.y), u2 = f2bf(a.z), u3 = f2bf(a.w);
    unsigned short u4 = f2bf(b.x), u5 = f2bf(b.y), u6 = f2bf(b.z), u7 = f2bf(b.w);
    float q0 = bf2f(u0), q1 = bf2f(u1), q2 = bf2f(u2), q3 = bf2f(u3);
    float q4 = bf2f(u4), q5 = bf2f(u5), q6 = bf2f(u6), q7 = bf2f(u7);
    float p = (q0*q0 + q1*q1 + q2*q2 + q3*q3) + (q4*q4 + q5*q5 + q6*q6 + q7*q7);

    unsigned short* Pu = (unsigned short*)P;
    int4 pack;
    pack.x = (int)((unsigned)u0 | ((unsigned)u1 << 16));
    pack.y = (int)((unsigned)u2 | ((unsigned)u3 << 16));
    pack.z = (int)((unsigned)u4 | ((unsigned)u5 << 16));
    pack.w = (int)((unsigned)u6 | ((unsigned)u7 << 16));
    *(int4*)(Pu + (size_t)r * CPAD + seg * 8) = pack;
    if (seg == 0) {
        int4 z; z.x = 0; z.y = 0; z.z = 0; z.w = 0;
        *(int4*)(Pu + (size_t)r * CPAD + 64) = z;
    }
    s_part[rl][seg] = p;
    __syncthreads();
    if (seg == 0) {
        float s = 0.f;
        #pragma unroll
        for (int k = 0; k < 8; ++k) s += s_part[rl][k];
        P[P_CSQ_F + r] = s;
    }
}

// ---------------- K1: two-half LDS-staged MFMA argmin, 8 blocks/CU ----------------
// 1024 blocks x 256 threads (4 waves); wave handles 32 samples; block 128.
// LDS 19.4 KB + VGPR<=64 -> 8 blocks/CU = 32 waves/CU.
__global__ __launch_bounds__(256, 8)
void deepect_argmin(const float* __restrict__ mb, const float* __restrict__ P,
                    float* __restrict__ out) {
    __shared__ __align__(16) unsigned short s_ctr[128][CPAD];  // 18432 B
    __shared__ float s_csq[KK];                                //  1024 B

    const int tid  = threadIdx.x;
    const int lane = tid & 63;
    const int w    = tid >> 6;       // wave 0..3
    const int g    = lane >> 4;
    const int c16  = lane & 15;

    const int sbase = blockIdx.x * 128 + w * 32;
    const int4* Pi = (const int4*)P;
    int4* Sd = (int4*)s_ctr;

    // ---- A fragments from global fp32 (issued first: in flight under staging) ----
    bf16x8 afr[2][2];
    float  xsq_rt[2];
    #pragma unroll
    for (int rt = 0; rt < 2; ++rt) {
        float px = 0.f;
        #pragma unroll
        for (int ks = 0; ks < 2; ++ks) {
            const float* rp = mb + (size_t)(sbase + rt * 16 + c16) * DD + g * 8 + ks * 32;
            float4 a = ((const float4*)rp)[0];
            float4 b = ((const float4*)rp)[1];
            bf16x8 f;
            f[0] = (short)f2bf(a.x); f[1] = (short)f2bf(a.y);
            f[2] = (short)f2bf(a.z); f[3] = (short)f2bf(a.w);
            f[4] = (short)f2bf(b.x); f[5] = (short)f2bf(b.y);
            f[6] = (short)f2bf(b.z); f[7] = (short)f2bf(b.w);
            afr[rt][ks] = f;
            px += a.x*a.x + a.y*a.y + a.z*a.z + a.w*a.w
                + b.x*b.x + b.y*b.y + b.z*b.z + b.w*b.w;
        }
        px += __shfl_xor(px, 16, 64);
        px += __shfl_xor(px, 32, 64);
        xsq_rt[rt] = px;
    }

    // ---- stage half 0 (centers 0..127) + all csq ----
    #pragma unroll
    for (int i = 0; i < 5; ++i) {
        int idx = i * 256 + tid;
        if (idx < P_HALF_I4) Sd[idx] = Pi[idx];
    }
    s_csq[tid] = P[P_CSQ_F + tid];   // blockDim == KK
    __syncthreads();

    float csqh[16];
    #pragma unroll
    for (int t = 0; t < 16; ++t) csqh[t] = -0.5f * s_csq[t * 16 + c16];

    float bestv[2][4];
    int   besti[2][4];
    #pragma unroll
    for (int rt = 0; rt < 2; ++rt)
        #pragma unroll
        for (int r = 0; r < 4; ++r) { bestv[rt][r] = -FLT_MAX; besti[rt][r] = 0; }

    // ---- scan half 0: tiles t = 0..7 ----
    #pragma unroll
    for (int t = 0; t < 8; ++t) {
        const bf16x8 b0 = *(const bf16x8*)&s_ctr[t * 16 + c16][g * 8];
        const bf16x8 b1 = *(const bf16x8*)&s_ctr[t * 16 + c16][g * 8 + 32];
        const int colidx = t * 16 + c16;
        #pragma unroll
        for (int rt = 0; rt < 2; ++rt) {
            f32x4 acc;
            acc[0] = csqh[t]; acc[1] = csqh[t]; acc[2] = csqh[t]; acc[3] = csqh[t];
            acc = __builtin_amdgcn_mfma_f32_16x16x32_bf16(afr[rt][0], b0, acc, 0, 0, 0);
            acc = __builtin_amdgcn_mfma_f32_16x16x32_bf16(afr[rt][1], b1, acc, 0, 0, 0);
            #pragma unroll
            for (int r = 0; r < 4; ++r) {
                if (acc[r] > bestv[rt][r]) { bestv[rt][r] = acc[r]; besti[rt][r] = colidx; }
            }
        }
    }
    __syncthreads();   // everyone done reading half 0

    // ---- stage half 1 (centers 128..255) into the same buffer ----
    #pragma unroll
    for (int i = 0; i < 5; ++i) {
        int idx = i * 256 + tid;
        if (idx < P_HALF_I4) Sd[idx] = Pi[P_HALF_I4 + idx];
    }
    __syncthreads();

    // ---- scan half 1: tiles t = 8..15 (LDS rows (t-8)*16, colidx +128) ----
    #pragma unroll
    for (int t = 8; t < 16; ++t) {
        const bf16x8 b0 = *(const bf16x8*)&s_ctr[(t - 8) * 16 + c16][g * 8];
        const bf16x8 b1 = *(const bf16x8*)&s_ctr[(t - 8) * 16 + c16][g * 8 + 32];
        const int colidx = t * 16 + c16;
        #pragma unroll
        for (int rt = 0; rt < 2; ++rt) {
            f32x4 acc;
            acc[0] = csqh[t]; acc[1] = csqh[t]; acc[2] = csqh[t]; acc[3] = csqh[t];
            acc = __builtin_amdgcn_mfma_f32_16x16x32_bf16(afr[rt][0], b0, acc, 0, 0, 0);
            acc = __builtin_amdgcn_mfma_f32_16x16x32_bf16(afr[rt][1], b1, acc, 0, 0, 0);
            #pragma unroll
            for (int r = 0; r < 4; ++r) {
                if (acc[r] > bestv[rt][r]) { bestv[rt][r] = acc[r]; besti[rt][r] = colidx; }
            }
        }
    }

    float* o_assign = out;
    float* o_mind   = out + NS;

    #pragma unroll
    for (int rt = 0; rt < 2; ++rt) {
        #pragma unroll
        for (int r = 0; r < 4; ++r) {
            float v  = bestv[rt][r];
            int   bi = besti[rt][r];
            #pragma unroll
            for (int off = 1; off < 16; off <<= 1) {
                float ov = __shfl_xor(v, off, 64);
                int   oi = __shfl_xor(bi, off, 64);
                if (ov > v || (ov == v && oi < bi)) { v = ov; bi = oi; }
            }
            int src = (lane & 48) | (g * 4 + r);
            float xq = __shfl(xsq_rt[rt], src, 64);
            float dsq = fmaxf(xq - 2.0f * v, 0.f);
            if (c16 == 0) {
                int s = sbase + rt * 16 + g * 4 + r;
                o_assign[s] = (float)bi;
                o_mind[s]   = sqrtf(dsq);
            }
        }
    }
}

// ---------------- K2: stats as one-hot GEMM (verified core; bf16 partials) ----------------
__global__ __launch_bounds__(512, 2)
void deepect_stats_gemm(const float* __restrict__ mb, const float* __restrict__ out,
                        float* __restrict__ ws) {
    __shared__ __align__(16) unsigned short s_xt[80][XTS];   // 42.2 KB
    __shared__ int s_bi[256];

    const int tid  = threadIdx.x;
    const int lane = tid & 63;
    const int w    = tid >> 6;
    const int g    = lane >> 4;
    const int c16  = lane & 15;
    const int base = blockIdx.x * 256;

    unsigned* xtw = (unsigned*)s_xt;

    for (int i = tid; i < 14 * XTSW; i += 512) xtw[66 * XTSW + i] = 0u;

    {
        const int dh = tid >> 7, sp = tid & 127;
        const float* r0 = mb + (size_t)(base + 2 * sp) * DD + dh * 16;
        const float* r1 = r0 + DD;
        #pragma unroll
        for (int q = 0; q < 4; ++q) {
            float4 a = ((const float4*)r0)[q];
            float4 b = ((const float4*)r1)[q];
            const int row = dh * 16 + q * 4;
            xtw[(row + 0) * XTSW + sp] = (unsigned)f2bf(a.x) | ((unsigned)f2bf(b.x) << 16);
            xtw[(row + 1) * XTSW + sp] = (unsigned)f2bf(a.y) | ((unsigned)f2bf(b.y) << 16);
            xtw[(row + 2) * XTSW + sp] = (unsigned)f2bf(a.z) | ((unsigned)f2bf(b.z) << 16);
            xtw[(row + 3) * XTSW + sp] = (unsigned)f2bf(a.w) | ((unsigned)f2bf(b.w) << 16);
        }
    }
    if (tid < 128) {
        const int sp = tid;
        float m0 = out[NS + base + 2 * sp];
        float m1 = out[NS + base + 2 * sp + 1];
        xtw[64 * XTSW + sp] = 0x3F803F80u;
        xtw[65 * XTSW + sp] = (unsigned)f2bf(m0 * m0) | ((unsigned)f2bf(m1 * m1) << 16);
    }
    if (tid < 256) s_bi[tid] = (int)out[base + tid];
    __syncthreads();

    f32x4 acc[2][5];
    #pragma unroll
    for (int L = 0; L < 2; ++L)
        #pragma unroll
        for (int dt = 0; dt < 5; ++dt) {
            acc[L][dt][0] = 0.f; acc[L][dt][1] = 0.f;
            acc[L][dt][2] = 0.f; acc[L][dt][3] = 0.f;
        }

    const int ml0 = w * 16 + c16;
    const int ml1 = (w + 8) * 16 + c16;

    #pragma unroll
    for (int ks = 0; ks < 8; ++ks) {
        const int kb = ks * 32 + g * 8;
        int4 bl = *(int4*)&s_bi[kb];
        int4 bh = *(int4*)&s_bi[kb + 4];
        bf16x8 bfrag[5];
        #pragma unroll
        for (int dt = 0; dt < 5; ++dt)
            bfrag[dt] = *(bf16x8*)&s_xt[dt * 16 + c16][kb];

        const int b0 = bl.x, b1 = bl.y, b2 = bl.z, b3 = bl.w;
        const int b4 = bh.x, b5 = bh.y, b6 = bh.z, b7 = bh.w;
        u32x4 u0, u1;
        u0[0] = (b0 == ml0 ? 0x3F80u : 0u) | (b1 == ml0 ? 0x3F800000u : 0u);
        u0[1] = (b2 == ml0 ? 0x3F80u : 0u) | (b3 == ml0 ? 0x3F800000u : 0u);
        u0[2] = (b4 == ml0 ? 0x3F80u : 0u) | (b5 == ml0 ? 0x3F800000u : 0u);
        u0[3] = (b6 == ml0 ? 0x3F80u : 0u) | (b7 == ml0 ? 0x3F800000u : 0u);
        u1[0] = (b0 == ml1 ? 0x3F80u : 0u) | (b1 == ml1 ? 0x3F800000u : 0u);
        u1[1] = (b2 == ml1 ? 0x3F80u : 0u) | (b3 == ml1 ? 0x3F800000u : 0u);
        u1[2] = (b4 == ml1 ? 0x3F80u : 0u) | (b5 == ml1 ? 0x3F800000u : 0u);
        u1[3] = (b6 == ml1 ? 0x3F80u : 0u) | (b7 == ml1 ? 0x3F800000u : 0u);
        bf16x8 a0 = __builtin_bit_cast(bf16x8, u0);
        bf16x8 a1 = __builtin_bit_cast(bf16x8, u1);

        #pragma unroll
        for (int dt = 0; dt < 5; ++dt) {
            acc[0][dt] = __builtin_amdgcn_mfma_f32_16x16x32_bf16(a0, bfrag[dt], acc[0][dt], 0, 0, 0);
            acc[1][dt] = __builtin_amdgcn_mfma_f32_16x16x32_bf16(a1, bfrag[dt], acc[1][dt], 0, 0, 0);
        }
    }

    unsigned short* dstu = (unsigned short*)ws + (size_t)blockIdx.x * NSTAT;
    #pragma unroll
    for (int L = 0; L < 2; ++L) {
        const int lt = (L == 0) ? w : (w + 8);
        #pragma unroll
        for (int dt = 0; dt < 5; ++dt) {
            const int col = dt * 16 + c16;
            #pragma unroll
            for (int r = 0; r < 4; ++r) {
                const int leaf = lt * 16 + g * 4 + r;
                if (col < 66) dstu[leaf * 66 + col] = f2bf(acc[L][dt][r]);
            }
        }
    }
}

// ---- two-stage reduce: bf16 copies -> f32 scratch -> output layout ----
__global__ void reduce_ws1(float* __restrict__ ws) {
    int gid = blockIdx.x * 256 + threadIdx.x;
    if (gid >= NSTAT * RGROUPS) return;
    int g = gid / NSTAT, e = gid - g * NSTAT;
    const unsigned short* src = (const unsigned short*)ws + (size_t)(g * RPER) * NSTAT + e;
    float s = 0.f;
    #pragma unroll 8
    for (int j = 0; j < RPER; ++j) s += bf2f(src[(size_t)j * NSTAT]);
    ws[SCR_OFF_F + (size_t)g * NSTAT + e] = s;
}

__global__ void reduce_ws2(const float* __restrict__ ws, float* __restrict__ o_stats) {
    int e = blockIdx.x * 256 + threadIdx.x;
    if (e >= NSTAT) return;
    float s = 0.f;
    #pragma unroll
    for (int g = 0; g < RGROUPS; ++g) s += ws[SCR_OFF_F + (size_t)g * NSTAT + e];
    int leaf = e / 66, c = e - leaf * 66;
    float* o_cnt = o_stats;
    float* o_sum = o_stats + KK;
    float* o_ssq = o_stats + KK + KK * DD;
    if (c < 64)       o_sum[leaf * 64 + c] = s;
    else if (c == 64) o_cnt[leaf] = s;
    else              o_ssq[leaf] = s;
}

// ---------------- fallback path (tiny ws) ----------------
__global__ __launch_bounds__(512, 2)
void deepect_argmin_fb(const float* __restrict__ mb, const float* __restrict__ ctr,
                       float* __restrict__ out) {
    __shared__ __align__(16) unsigned short s_ctr[KK][CPAD];
    __shared__ float s_csq[KK];

    const int tid  = threadIdx.x;
    const int lane = tid & 63;
    const int w    = tid >> 6;
    const int g    = lane >> 4;
    const int c16  = lane & 15;

    for (int idx = tid; idx < KK * 16; idx += 512) {
        int row = idx >> 4, f4 = idx & 15;
        float4 v = ((const float4*)(ctr + row * DD))[f4];
        ushort4 b;
        b.x = f2bf(v.x); b.y = f2bf(v.y); b.z = f2bf(v.z); b.w = f2bf(v.w);
        *(ushort4*)&s_ctr[row][f4 * 4] = b;
    }
    __syncthreads();

    if (tid < KK) {
        float acc = 0.f;
        #pragma unroll
        for (int j = 0; j < 16; ++j) {
            ushort4 b = *(ushort4*)&s_ctr[tid][j * 4];
            float x0 = bf2f(b.x), x1 = bf2f(b.y), x2 = bf2f(b.z), x3 = bf2f(b.w);
            acc += x0 * x0 + x1 * x1 + x2 * x2 + x3 * x3;
        }
        s_csq[tid] = acc;
    }
    __syncthreads();

    float csqh[16];
    #pragma unroll
    for (int t = 0; t < 16; ++t) csqh[t] = -0.5f * s_csq[t * 16 + c16];

    const int sbase = blockIdx.x * 256 + w * 32;

    bf16x8 afr[2][2];
    float  xsq_rt[2];
    #pragma unroll
    for (int rt = 0; rt < 2; ++rt) {
        float px = 0.f;
        #pragma unroll
        for (int ks = 0; ks < 2; ++ks) {
            const float* rp = mb + (size_t)(sbase + rt * 16 + c16) * DD + g * 8 + ks * 32;
            float4 a = ((const float4*)rp)[0];
            float4 b = ((const float4*)rp)[1];
            bf16x8 f;
            f[0] = (short)f2bf(a.x); f[1] = (short)f2bf(a.y);
            f[2] = (short)f2bf(a.z); f[3] = (short)f2bf(a.w);
            f[4] = (short)f2bf(b.x); f[5] = (short)f2bf(b.y);
            f[6] = (short)f2bf(b.z); f[7] = (short)f2bf(b.w);
            afr[rt][ks] = f;
            px += a.x*a.x + a.y*a.y + a.z*a.z + a.w*a.w
                + b.x*b.x + b.y*b.y + b.z*b.z + b.w*b.w;
        }
        px += __shfl_xor(px, 16, 64);
        px += __shfl_xor(px, 32, 64);
        xsq_rt[rt] = px;
    }

    float bestv[2][4];
    int   besti[2][4];
    #pragma unroll
    for (int rt = 0; rt < 2; ++rt)
        #pragma unroll
        for (int r = 0; r < 4; ++r) { bestv[rt][r] = -FLT_MAX; besti[rt][r] = 0; }

    #pragma unroll
    for (int t = 0; t < 16; ++t) {
        bf16x8 b0 = *(bf16x8*)&s_ctr[t * 16 + c16][g * 8];
        bf16x8 b1 = *(bf16x8*)&s_ctr[t * 16 + c16][g * 8 + 32];
        const int colidx = t * 16 + c16;
        #pragma unroll
        for (int rt = 0; rt < 2; ++rt) {
            f32x4 acc;
            acc[0] = csqh[t]; acc[1] = csqh[t]; acc[2] = csqh[t]; acc[3] = csqh[t];
            acc = __builtin_amdgcn_mfma_f32_16x16x32_bf16(afr[rt][0], b0, acc, 0, 0, 0);
            acc = __builtin_amdgcn_mfma_f32_16x16x32_bf16(afr[rt][1], b1, acc, 0, 0, 0);
            #pragma unroll
            for (int r = 0; r < 4; ++r) {
                if (acc[r] > bestv[rt][r]) { bestv[rt][r] = acc[r]; besti[rt][r] = colidx; }
            }
        }
    }

    float* o_assign = out;
    float* o_mind   = out + NS;

    #pragma unroll
    for (int rt = 0; rt < 2; ++rt) {
        #pragma unroll
        for (int r = 0; r < 4; ++r) {
            float v  = bestv[rt][r];
            int   bi = besti[rt][r];
            #pragma unroll
            for (int off = 1; off < 16; off <<= 1) {
                float ov = __shfl_xor(v, off, 64);
                int   oi = __shfl_xor(bi, off, 64);
                if (ov > v || (ov == v && oi < bi)) { v = ov; bi = oi; }
            }
            int src = (lane & 48) | (g * 4 + r);
            float xq = __shfl(xsq_rt[rt], src, 64);
            float dsq = fmaxf(xq - 2.0f * v, 0.f);
            if (c16 == 0) {
                int s = sbase + rt * 16 + g * 4 + r;
                o_assign[s] = (float)bi;
                o_mind[s]   = sqrtf(dsq);
            }
        }
    }
}

__global__ __launch_bounds__(512)
void deepect_stats_atomic(const float* __restrict__ mb, const float* __restrict__ out,
                          float* __restrict__ o_stats) {
    __shared__ float s_cnt[KK];
    __shared__ float s_ssq[KK];
    __shared__ float s_sum[KK][65];

    const int tid = threadIdx.x;
    for (int idx = tid; idx < KK; idx += 512) { s_cnt[idx] = 0.f; s_ssq[idx] = 0.f; }
    for (int idx = tid; idx < KK * 65; idx += 512) ((float*)s_sum)[idx] = 0.f;
    __syncthreads();

    const int grp = tid >> 4;
    const int d4  = tid & 15;
    const int ibase = blockIdx.x * 512 + grp * 16;

    for (int s = 0; s < 16; ++s) {
        const int i = ibase + s;
        const int bi = (int)out[i];
        float4 v = ((const float4*)(mb + (size_t)i * DD))[d4];
        atomicAdd(&s_sum[bi][d4 * 4 + 0], v.x);
        atomicAdd(&s_sum[bi][d4 * 4 + 1], v.y);
        atomicAdd(&s_sum[bi][d4 * 4 + 2], v.z);
        atomicAdd(&s_sum[bi][d4 * 4 + 3], v.w);
        if (d4 == 0) {
            const float md = out[NS + i];
            atomicAdd(&s_cnt[bi], 1.0f);
            atomicAdd(&s_ssq[bi], md * md);
        }
    }
    __syncthreads();

    for (int idx = tid; idx < KK; idx += 512) {
        atomicAdd(&o_stats[idx], s_cnt[idx]);
        atomicAdd(&o_stats[KK + KK * DD + idx], s_ssq[idx]);
    }
    for (int idx = tid; idx < KK * DD; idx += 512)
        atomicAdd(&o_stats[KK + idx], s_sum[idx >> 6][idx & 63]);
}

extern "C" void kernel_launch(void* const* d_in, const int* in_sizes, int n_in,
                              void* d_out, int out_size, void* d_ws, size_t ws_size,
                              hipStream_t stream) {
    const float* mb  = (const float*)d_in[0];
    const float* ctr = (const float*)d_in[1];
    float* out = (float*)d_out;
    float* o_stats = out + 2 * NS;
    float* ws = (float*)d_ws;

    const size_t need = (P_OFF_F + P_CSQ_F + KK) * sizeof(float);

    if (ws_size >= need) {
        float* P = ws + P_OFF_F;
        hipLaunchKernelGGL(prep_centers, dim3(8), dim3(256), 0, stream, ctr, P);
        hipLaunchKernelGGL(deepect_argmin, dim3(NS / 128), dim3(256), 0, stream,
                           mb, P, out);
        hipLaunchKernelGGL(deepect_stats_gemm, dim3(NS / 256), dim3(512), 0, stream,
                           mb, out, ws);
        hipLaunchKernelGGL(reduce_ws1, dim3((NSTAT * RGROUPS + 255) / 256), dim3(256),
                           0, stream, ws);
        hipLaunchKernelGGL(reduce_ws2, dim3((NSTAT + 255) / 256), dim3(256), 0, stream,
                           ws, o_stats);
    } else {
        hipLaunchKernelGGL(zero_buf, dim3((NSTAT + 255) / 256), dim3(256), 0, stream,
                           o_stats, NSTAT);
        hipLaunchKernelGGL(deepect_argmin_fb, dim3(NS / 256), dim3(512), 0, stream,
                           mb, ctr, out);
        hipLaunchKernelGGL(deepect_stats_atomic, dim3(NS / 512), dim3(512), 0, stream,
                           mb, out, o_stats);
    }
}

// Round 14
// 62.127 us; speedup vs baseline: 2.0354x; 2.0354x over previous
//
#include <hip/hip_runtime.h>
#include <hip/hip_bf16.h>
#include <float.h>

#define NS 131072
#define DD 64
#define KK 256
#define CPAD 72      // center image row stride in bf16 (144 B, 16B-aligned)
#define NSTAT 16896  // 256 * 66  (cols 0..63 sums | 64 cnt | 65 ssq)
#define XTS 264      // xT row stride in bf16 (528B rows, 16B-aligned)
#define XTSW 132     // XTS/2 dwords
#define NCOPY 512
#define RGROUPS 16
#define RPER 32      // NCOPY / RGROUPS
// ws layout:
//   [0, NCOPY*NSTAT) as ushort bf16   : per-block stat partials (17.3 MB)
//   SCR_OFF_F  + [0, RGROUPS*NSTAT)   : f32 stage-1 scratch
//   P_OFF_F    + [0, 9216)            : bf16 center image [256][72] (36864 B)
//   P_OFF_F    + 9216 + [0,256)       : f32 csq
#define SCR_OFF_F ((size_t)NCOPY * NSTAT / 2)
#define P_OFF_F   (SCR_OFF_F + (size_t)RGROUPS * NSTAT)
#define P_CSQ_F 9216
#define P_IMG_I4 2304
#define P_HALF_I4 1152   // int4 count of one 128-center half

typedef __attribute__((ext_vector_type(8))) short bf16x8;
typedef __attribute__((ext_vector_type(4))) float f32x4;
typedef __attribute__((ext_vector_type(4))) unsigned int u32x4;

// d_out layout (float32 values):
//   [0, NS) assignments | [NS,2NS) min_dists | stats: cnt[256] | sums[256*64] | ssq[256]

__global__ void zero_buf(float* __restrict__ p, int n) {
    int i = blockIdx.x * 256 + threadIdx.x;
    if (i < n) p[i] = 0.f;
}

__device__ inline unsigned short f2bf(float f) {
    union { __hip_bfloat16 h; unsigned short u; } v;
    v.h = __float2bfloat16(f);          // RNE
    return v.u;
}
__device__ inline float bf2f(unsigned short b) {
    return __uint_as_float(((unsigned)b) << 16);
}

// ---------------- K0: prep centers (bf16 image + pads + csq) ----------------
__global__ void prep_centers(const float* __restrict__ ctr, float* __restrict__ P) {
    __shared__ float s_part[32][9];
    const int t = threadIdx.x;
    const int rl = t >> 3, seg = t & 7;
    const int r = blockIdx.x * 32 + rl;
    const float* rp = ctr + r * DD + seg * 8;
    float4 a = ((const float4*)rp)[0];
    float4 b = ((const float4*)rp)[1];
    unsigned short u0 = f2bf(a.x), u1 = f2bf(a.y), u2 = f2bf(a.z), u3 = f2bf(a.w);
    unsigned short u4 = f2bf(b.x), u5 = f2bf(b.y), u6 = f2bf(b.z), u7 = f2bf(b.w);
    float q0 = bf2f(u0), q1 = bf2f(u1), q2 = bf2f(u2), q3 = bf2f(u3);
    float q4 = bf2f(u4), q5 = bf2f(u5), q6 = bf2f(u6), q7 = bf2f(u7);
    float p = (q0*q0 + q1*q1 + q2*q2 + q3*q3) + (q4*q4 + q5*q5 + q6*q6 + q7*q7);

    unsigned short* Pu = (unsigned short*)P;
    int4 pack;
    pack.x = (int)((unsigned)u0 | ((unsigned)u1 << 16));
    pack.y = (int)((unsigned)u2 | ((unsigned)u3 << 16));
    pack.z = (int)((unsigned)u4 | ((unsigned)u5 << 16));
    pack.w = (int)((unsigned)u6 | ((unsigned)u7 << 16));
    *(int4*)(Pu + (size_t)r * CPAD + seg * 8) = pack;
    if (seg == 0) {
        int4 z; z.x = 0; z.y = 0; z.z = 0; z.w = 0;
        *(int4*)(Pu + (size_t)r * CPAD + 64) = z;
    }
    s_part[rl][seg] = p;
    __syncthreads();
    if (seg == 0) {
        float s = 0.f;
        #pragma unroll
        for (int k = 0; k < 8; ++k) s += s_part[rl][k];
        P[P_CSQ_F + r] = s;
    }
}

// ---------------- K1: two-half LDS-staged MFMA argmin ----------------
// 1024 blocks x 256 threads (4 waves); wave handles 32 samples; block 128.
// LDS 19.5 KB; launch_bounds(256,4) -> 128-VGPR budget, core compiles to ~64
// VGPR (r12-measured) so HW occupancy = min(8 LDS, 8 VGPR) = 8 blocks/CU.
__global__ __launch_bounds__(256, 4)
void deepect_argmin(const float* __restrict__ mb, const float* __restrict__ P,
                    float* __restrict__ out) {
    __shared__ __align__(16) unsigned short s_ctr[128][CPAD];  // 18432 B
    __shared__ float s_csq[KK];                                //  1024 B

    const int tid  = threadIdx.x;
    const int lane = tid & 63;
    const int w    = tid >> 6;       // wave 0..3
    const int g    = lane >> 4;
    const int c16  = lane & 15;

    const int sbase = blockIdx.x * 128 + w * 32;
    const int4* Pi = (const int4*)P;
    int4* Sd = (int4*)s_ctr;

    // ---- A fragments from global fp32 (issued first: in flight under staging) ----
    bf16x8 afr[2][2];
    float  xsq_rt[2];
    #pragma unroll
    for (int rt = 0; rt < 2; ++rt) {
        float px = 0.f;
        #pragma unroll
        for (int ks = 0; ks < 2; ++ks) {
            const float* rp = mb + (size_t)(sbase + rt * 16 + c16) * DD + g * 8 + ks * 32;
            float4 a = ((const float4*)rp)[0];
            float4 b = ((const float4*)rp)[1];
            bf16x8 f;
            f[0] = (short)f2bf(a.x); f[1] = (short)f2bf(a.y);
            f[2] = (short)f2bf(a.z); f[3] = (short)f2bf(a.w);
            f[4] = (short)f2bf(b.x); f[5] = (short)f2bf(b.y);
            f[6] = (short)f2bf(b.z); f[7] = (short)f2bf(b.w);
            afr[rt][ks] = f;
            px += a.x*a.x + a.y*a.y + a.z*a.z + a.w*a.w
                + b.x*b.x + b.y*b.y + b.z*b.z + b.w*b.w;
        }
        px += __shfl_xor(px, 16, 64);
        px += __shfl_xor(px, 32, 64);
        xsq_rt[rt] = px;
    }

    // ---- stage half 0 (centers 0..127) + all csq ----
    #pragma unroll
    for (int i = 0; i < 5; ++i) {
        int idx = i * 256 + tid;
        if (idx < P_HALF_I4) Sd[idx] = Pi[idx];
    }
    s_csq[tid] = P[P_CSQ_F + tid];   // blockDim == KK
    __syncthreads();

    float csqh[16];
    #pragma unroll
    for (int t = 0; t < 16; ++t) csqh[t] = -0.5f * s_csq[t * 16 + c16];

    float bestv[2][4];
    int   besti[2][4];
    #pragma unroll
    for (int rt = 0; rt < 2; ++rt)
        #pragma unroll
        for (int r = 0; r < 4; ++r) { bestv[rt][r] = -FLT_MAX; besti[rt][r] = 0; }

    // ---- scan half 0: tiles t = 0..7 ----
    #pragma unroll
    for (int t = 0; t < 8; ++t) {
        const bf16x8 b0 = *(const bf16x8*)&s_ctr[t * 16 + c16][g * 8];
        const bf16x8 b1 = *(const bf16x8*)&s_ctr[t * 16 + c16][g * 8 + 32];
        const int colidx = t * 16 + c16;
        #pragma unroll
        for (int rt = 0; rt < 2; ++rt) {
            f32x4 acc;
            acc[0] = csqh[t]; acc[1] = csqh[t]; acc[2] = csqh[t]; acc[3] = csqh[t];
            acc = __builtin_amdgcn_mfma_f32_16x16x32_bf16(afr[rt][0], b0, acc, 0, 0, 0);
            acc = __builtin_amdgcn_mfma_f32_16x16x32_bf16(afr[rt][1], b1, acc, 0, 0, 0);
            #pragma unroll
            for (int r = 0; r < 4; ++r) {
                if (acc[r] > bestv[rt][r]) { bestv[rt][r] = acc[r]; besti[rt][r] = colidx; }
            }
        }
    }
    __syncthreads();   // everyone done reading half 0

    // ---- stage half 1 (centers 128..255) into the same buffer ----
    #pragma unroll
    for (int i = 0; i < 5; ++i) {
        int idx = i * 256 + tid;
        if (idx < P_HALF_I4) Sd[idx] = Pi[P_HALF_I4 + idx];
    }
    __syncthreads();

    // ---- scan half 1: tiles t = 8..15 (LDS rows (t-8)*16, colidx +128) ----
    #pragma unroll
    for (int t = 8; t < 16; ++t) {
        const bf16x8 b0 = *(const bf16x8*)&s_ctr[(t - 8) * 16 + c16][g * 8];
        const bf16x8 b1 = *(const bf16x8*)&s_ctr[(t - 8) * 16 + c16][g * 8 + 32];
        const int colidx = t * 16 + c16;
        #pragma unroll
        for (int rt = 0; rt < 2; ++rt) {
            f32x4 acc;
            acc[0] = csqh[t]; acc[1] = csqh[t]; acc[2] = csqh[t]; acc[3] = csqh[t];
            acc = __builtin_amdgcn_mfma_f32_16x16x32_bf16(afr[rt][0], b0, acc, 0, 0, 0);
            acc = __builtin_amdgcn_mfma_f32_16x16x32_bf16(afr[rt][1], b1, acc, 0, 0, 0);
            #pragma unroll
            for (int r = 0; r < 4; ++r) {
                if (acc[r] > bestv[rt][r]) { bestv[rt][r] = acc[r]; besti[rt][r] = colidx; }
            }
        }
    }

    float* o_assign = out;
    float* o_mind   = out + NS;

    #pragma unroll
    for (int rt = 0; rt < 2; ++rt) {
        #pragma unroll
        for (int r = 0; r < 4; ++r) {
            float v  = bestv[rt][r];
            int   bi = besti[rt][r];
            #pragma unroll
            for (int off = 1; off < 16; off <<= 1) {
                float ov = __shfl_xor(v, off, 64);
                int   oi = __shfl_xor(bi, off, 64);
                if (ov > v || (ov == v && oi < bi)) { v = ov; bi = oi; }
            }
            int src = (lane & 48) | (g * 4 + r);
            float xq = __shfl(xsq_rt[rt], src, 64);
            float dsq = fmaxf(xq - 2.0f * v, 0.f);
            if (c16 == 0) {
                int s = sbase + rt * 16 + g * 4 + r;
                o_assign[s] = (float)bi;
                o_mind[s]   = sqrtf(dsq);
            }
        }
    }
}

// ---------------- K2: stats as one-hot GEMM (verified core; bf16 partials) ----------------
__global__ __launch_bounds__(512, 2)
void deepect_stats_gemm(const float* __restrict__ mb, const float* __restrict__ out,
                        float* __restrict__ ws) {
    __shared__ __align__(16) unsigned short s_xt[80][XTS];   // 42.2 KB
    __shared__ int s_bi[256];

    const int tid  = threadIdx.x;
    const int lane = tid & 63;
    const int w    = tid >> 6;
    const int g    = lane >> 4;
    const int c16  = lane & 15;
    const int base = blockIdx.x * 256;

    unsigned* xtw = (unsigned*)s_xt;

    for (int i = tid; i < 14 * XTSW; i += 512) xtw[66 * XTSW + i] = 0u;

    {
        const int dh = tid >> 7, sp = tid & 127;
        const float* r0 = mb + (size_t)(base + 2 * sp) * DD + dh * 16;
        const float* r1 = r0 + DD;
        #pragma unroll
        for (int q = 0; q < 4; ++q) {
            float4 a = ((const float4*)r0)[q];
            float4 b = ((const float4*)r1)[q];
            const int row = dh * 16 + q * 4;
            xtw[(row + 0) * XTSW + sp] = (unsigned)f2bf(a.x) | ((unsigned)f2bf(b.x) << 16);
            xtw[(row + 1) * XTSW + sp] = (unsigned)f2bf(a.y) | ((unsigned)f2bf(b.y) << 16);
            xtw[(row + 2) * XTSW + sp] = (unsigned)f2bf(a.z) | ((unsigned)f2bf(b.z) << 16);
            xtw[(row + 3) * XTSW + sp] = (unsigned)f2bf(a.w) | ((unsigned)f2bf(b.w) << 16);
        }
    }
    if (tid < 128) {
        const int sp = tid;
        float m0 = out[NS + base + 2 * sp];
        float m1 = out[NS + base + 2 * sp + 1];
        xtw[64 * XTSW + sp] = 0x3F803F80u;
        xtw[65 * XTSW + sp] = (unsigned)f2bf(m0 * m0) | ((unsigned)f2bf(m1 * m1) << 16);
    }
    if (tid < 256) s_bi[tid] = (int)out[base + tid];
    __syncthreads();

    f32x4 acc[2][5];
    #pragma unroll
    for (int L = 0; L < 2; ++L)
        #pragma unroll
        for (int dt = 0; dt < 5; ++dt) {
            acc[L][dt][0] = 0.f; acc[L][dt][1] = 0.f;
            acc[L][dt][2] = 0.f; acc[L][dt][3] = 0.f;
        }

    const int ml0 = w * 16 + c16;
    const int ml1 = (w + 8) * 16 + c16;

    #pragma unroll
    for (int ks = 0; ks < 8; ++ks) {
        const int kb = ks * 32 + g * 8;
        int4 bl = *(int4*)&s_bi[kb];
        int4 bh = *(int4*)&s_bi[kb + 4];
        bf16x8 bfrag[5];
        #pragma unroll
        for (int dt = 0; dt < 5; ++dt)
            bfrag[dt] = *(bf16x8*)&s_xt[dt * 16 + c16][kb];

        const int b0 = bl.x, b1 = bl.y, b2 = bl.z, b3 = bl.w;
        const int b4 = bh.x, b5 = bh.y, b6 = bh.z, b7 = bh.w;
        u32x4 u0, u1;
        u0[0] = (b0 == ml0 ? 0x3F80u : 0u) | (b1 == ml0 ? 0x3F800000u : 0u);
        u0[1] = (b2 == ml0 ? 0x3F80u : 0u) | (b3 == ml0 ? 0x3F800000u : 0u);
        u0[2] = (b4 == ml0 ? 0x3F80u : 0u) | (b5 == ml0 ? 0x3F800000u : 0u);
        u0[3] = (b6 == ml0 ? 0x3F80u : 0u) | (b7 == ml0 ? 0x3F800000u : 0u);
        u1[0] = (b0 == ml1 ? 0x3F80u : 0u) | (b1 == ml1 ? 0x3F800000u : 0u);
        u1[1] = (b2 == ml1 ? 0x3F80u : 0u) | (b3 == ml1 ? 0x3F800000u : 0u);
        u1[2] = (b4 == ml1 ? 0x3F80u : 0u) | (b5 == ml1 ? 0x3F800000u : 0u);
        u1[3] = (b6 == ml1 ? 0x3F80u : 0u) | (b7 == ml1 ? 0x3F800000u : 0u);
        bf16x8 a0 = __builtin_bit_cast(bf16x8, u0);
        bf16x8 a1 = __builtin_bit_cast(bf16x8, u1);

        #pragma unroll
        for (int dt = 0; dt < 5; ++dt) {
            acc[0][dt] = __builtin_amdgcn_mfma_f32_16x16x32_bf16(a0, bfrag[dt], acc[0][dt], 0, 0, 0);
            acc[1][dt] = __builtin_amdgcn_mfma_f32_16x16x32_bf16(a1, bfrag[dt], acc[1][dt], 0, 0, 0);
        }
    }

    unsigned short* dstu = (unsigned short*)ws + (size_t)blockIdx.x * NSTAT;
    #pragma unroll
    for (int L = 0; L < 2; ++L) {
        const int lt = (L == 0) ? w : (w + 8);
        #pragma unroll
        for (int dt = 0; dt < 5; ++dt) {
            const int col = dt * 16 + c16;
            #pragma unroll
            for (int r = 0; r < 4; ++r) {
                const int leaf = lt * 16 + g * 4 + r;
                if (col < 66) dstu[leaf * 66 + col] = f2bf(acc[L][dt][r]);
            }
        }
    }
}

// ---- two-stage reduce: bf16 copies -> f32 scratch -> output layout ----
__global__ void reduce_ws1(float* __restrict__ ws) {
    int gid = blockIdx.x * 256 + threadIdx.x;
    if (gid >= NSTAT * RGROUPS) return;
    int g = gid / NSTAT, e = gid - g * NSTAT;
    const unsigned short* src = (const unsigned short*)ws + (size_t)(g * RPER) * NSTAT + e;
    float s = 0.f;
    #pragma unroll 8
    for (int j = 0; j < RPER; ++j) s += bf2f(src[(size_t)j * NSTAT]);
    ws[SCR_OFF_F + (size_t)g * NSTAT + e] = s;
}

__global__ void reduce_ws2(const float* __restrict__ ws, float* __restrict__ o_stats) {
    int e = blockIdx.x * 256 + threadIdx.x;
    if (e >= NSTAT) return;
    float s = 0.f;
    #pragma unroll
    for (int g = 0; g < RGROUPS; ++g) s += ws[SCR_OFF_F + (size_t)g * NSTAT + e];
    int leaf = e / 66, c = e - leaf * 66;
    float* o_cnt = o_stats;
    float* o_sum = o_stats + KK;
    float* o_ssq = o_stats + KK + KK * DD;
    if (c < 64)       o_sum[leaf * 64 + c] = s;
    else if (c == 64) o_cnt[leaf] = s;
    else              o_ssq[leaf] = s;
}

// ---------------- fallback path (tiny ws) ----------------
__global__ __launch_bounds__(512, 2)
void deepect_argmin_fb(const float* __restrict__ mb, const float* __restrict__ ctr,
                       float* __restrict__ out) {
    __shared__ __align__(16) unsigned short s_ctr[KK][CPAD];
    __shared__ float s_csq[KK];

    const int tid  = threadIdx.x;
    const int lane = tid & 63;
    const int w    = tid >> 6;
    const int g    = lane >> 4;
    const int c16  = lane & 15;

    for (int idx = tid; idx < KK * 16; idx += 512) {
        int row = idx >> 4, f4 = idx & 15;
        float4 v = ((const float4*)(ctr + row * DD))[f4];
        ushort4 b;
        b.x = f2bf(v.x); b.y = f2bf(v.y); b.z = f2bf(v.z); b.w = f2bf(v.w);
        *(ushort4*)&s_ctr[row][f4 * 4] = b;
    }
    __syncthreads();

    if (tid < KK) {
        float acc = 0.f;
        #pragma unroll
        for (int j = 0; j < 16; ++j) {
            ushort4 b = *(ushort4*)&s_ctr[tid][j * 4];
            float x0 = bf2f(b.x), x1 = bf2f(b.y), x2 = bf2f(b.z), x3 = bf2f(b.w);
            acc += x0 * x0 + x1 * x1 + x2 * x2 + x3 * x3;
        }
        s_csq[tid] = acc;
    }
    __syncthreads();

    float csqh[16];
    #pragma unroll
    for (int t = 0; t < 16; ++t) csqh[t] = -0.5f * s_csq[t * 16 + c16];

    const int sbase = blockIdx.x * 256 + w * 32;

    bf16x8 afr[2][2];
    float  xsq_rt[2];
    #pragma unroll
    for (int rt = 0; rt < 2; ++rt) {
        float px = 0.f;
        #pragma unroll
        for (int ks = 0; ks < 2; ++ks) {
            const float* rp = mb + (size_t)(sbase + rt * 16 + c16) * DD + g * 8 + ks * 32;
            float4 a = ((const float4*)rp)[0];
            float4 b = ((const float4*)rp)[1];
            bf16x8 f;
            f[0] = (short)f2bf(a.x); f[1] = (short)f2bf(a.y);
            f[2] = (short)f2bf(a.z); f[3] = (short)f2bf(a.w);
            f[4] = (short)f2bf(b.x); f[5] = (short)f2bf(b.y);
            f[6] = (short)f2bf(b.z); f[7] = (short)f2bf(b.w);
            afr[rt][ks] = f;
            px += a.x*a.x + a.y*a.y + a.z*a.z + a.w*a.w
                + b.x*b.x + b.y*b.y + b.z*b.z + b.w*b.w;
        }
        px += __shfl_xor(px, 16, 64);
        px += __shfl_xor(px, 32, 64);
        xsq_rt[rt] = px;
    }

    float bestv[2][4];
    int   besti[2][4];
    #pragma unroll
    for (int rt = 0; rt < 2; ++rt)
        #pragma unroll
        for (int r = 0; r < 4; ++r) { bestv[rt][r] = -FLT_MAX; besti[rt][r] = 0; }

    #pragma unroll
    for (int t = 0; t < 16; ++t) {
        bf16x8 b0 = *(bf16x8*)&s_ctr[t * 16 + c16][g * 8];
        bf16x8 b1 = *(bf16x8*)&s_ctr[t * 16 + c16][g * 8 + 32];
        const int colidx = t * 16 + c16;
        #pragma unroll
        for (int rt = 0; rt < 2; ++rt) {
            f32x4 acc;
            acc[0] = csqh[t]; acc[1] = csqh[t]; acc[2] = csqh[t]; acc[3] = csqh[t];
            acc = __builtin_amdgcn_mfma_f32_16x16x32_bf16(afr[rt][0], b0, acc, 0, 0, 0);
            acc = __builtin_amdgcn_mfma_f32_16x16x32_bf16(afr[rt][1], b1, acc, 0, 0, 0);
            #pragma unroll
            for (int r = 0; r < 4; ++r) {
                if (acc[r] > bestv[rt][r]) { bestv[rt][r] = acc[r]; besti[rt][r] = colidx; }
            }
        }
    }

    float* o_assign = out;
    float* o_mind   = out + NS;

    #pragma unroll
    for (int rt = 0; rt < 2; ++rt) {
        #pragma unroll
        for (int r = 0; r < 4; ++r) {
            float v  = bestv[rt][r];
            int   bi = besti[rt][r];
            #pragma unroll
            for (int off = 1; off < 16; off <<= 1) {
                float ov = __shfl_xor(v, off, 64);
                int   oi = __shfl_xor(bi, off, 64);
                if (ov > v || (ov == v && oi < bi)) { v = ov; bi = oi; }
            }
            int src = (lane & 48) | (g * 4 + r);
            float xq = __shfl(xsq_rt[rt], src, 64);
            float dsq = fmaxf(xq - 2.0f * v, 0.f);
            if (c16 == 0) {
                int s = sbase + rt * 16 + g * 4 + r;
                o_assign[s] = (float)bi;
                o_mind[s]   = sqrtf(dsq);
            }
        }
    }
}

__global__ __launch_bounds__(512)
void deepect_stats_atomic(const float* __restrict__ mb, const float* __restrict__ out,
                          float* __restrict__ o_stats) {
    __shared__ float s_cnt[KK];
    __shared__ float s_ssq[KK];
    __shared__ float s_sum[KK][65];

    const int tid = threadIdx.x;
    for (int idx = tid; idx < KK; idx += 512) { s_cnt[idx] = 0.f; s_ssq[idx] = 0.f; }
    for (int idx = tid; idx < KK * 65; idx += 512) ((float*)s_sum)[idx] = 0.f;
    __syncthreads();

    const int grp = tid >> 4;
    const int d4  = tid & 15;
    const int ibase = blockIdx.x * 512 + grp * 16;

    for (int s = 0; s < 16; ++s) {
        const int i = ibase + s;
        const int bi = (int)out[i];
        float4 v = ((const float4*)(mb + (size_t)i * DD))[d4];
        atomicAdd(&s_sum[bi][d4 * 4 + 0], v.x);
        atomicAdd(&s_sum[bi][d4 * 4 + 1], v.y);
        atomicAdd(&s_sum[bi][d4 * 4 + 2], v.z);
        atomicAdd(&s_sum[bi][d4 * 4 + 3], v.w);
        if (d4 == 0) {
            const float md = out[NS + i];
            atomicAdd(&s_cnt[bi], 1.0f);
            atomicAdd(&s_ssq[bi], md * md);
        }
    }
    __syncthreads();

    for (int idx = tid; idx < KK; idx += 512) {
        atomicAdd(&o_stats[idx], s_cnt[idx]);
        atomicAdd(&o_stats[KK + KK * DD + idx], s_ssq[idx]);
    }
    for (int idx = tid; idx < KK * DD; idx += 512)
        atomicAdd(&o_stats[KK + idx], s_sum[idx >> 6][idx & 63]);
}

extern "C" void kernel_launch(void* const* d_in, const int* in_sizes, int n_in,
                              void* d_out, int out_size, void* d_ws, size_t ws_size,
                              hipStream_t stream) {
    const float* mb  = (const float*)d_in[0];
    const float* ctr = (const float*)d_in[1];
    float* out = (float*)d_out;
    float* o_stats = out + 2 * NS;
    float* ws = (float*)d_ws;

    const size_t need = (P_OFF_F + P_CSQ_F + KK) * sizeof(float);

    if (ws_size >= need) {
        float* P = ws + P_OFF_F;
        hipLaunchKernelGGL(prep_centers, dim3(8), dim3(256), 0, stream, ctr, P);
        hipLaunchKernelGGL(deepect_argmin, dim3(NS / 128), dim3(256), 0, stream,
                           mb, P, out);
        hipLaunchKernelGGL(deepect_stats_gemm, dim3(NS / 256), dim3(512), 0, stream,
                           mb, out, ws);
        hipLaunchKernelGGL(reduce_ws1, dim3((NSTAT * RGROUPS + 255) / 256), dim3(256),
                           0, stream, ws);
        hipLaunchKernelGGL(reduce_ws2, dim3((NSTAT + 255) / 256), dim3(256), 0, stream,
                           ws, o_stats);
    } else {
        hipLaunchKernelGGL(zero_buf, dim3((NSTAT + 255) / 256), dim3(256), 0, stream,
                           o_stats, NSTAT);
        hipLaunchKernelGGL(deepect_argmin_fb, dim3(NS / 256), dim3(512), 0, stream,
                           mb, ctr, out);
        hipLaunchKernelGGL(deepect_stats_atomic, dim3(NS / 512), dim3(512), 0, stream,
                           mb, out, o_stats);
    }
}

// Round 15
// 50.443 us; speedup vs baseline: 2.5068x; 1.2316x over previous
//
#include <hip/hip_runtime.h>
#include <float.h>

#define NS 131072
#define DD 64
#define KK 256
#define CPAD 72     // argmin center tile pad (verified)
#define NSTAT 16896 // 256 * 66  (cols 0..63 sums | 64 cnt | 65 ssq)
#define XTS 264     // xT row stride in bf16
#define XTSW 132    // XTS/2 dwords
#define NCOPY 512
#define RGROUPS 16
#define RPER 32     // NCOPY / RGROUPS

typedef __attribute__((ext_vector_type(8))) short bf16x8;
typedef __attribute__((ext_vector_type(4))) float f32x4;
typedef __attribute__((ext_vector_type(4))) unsigned int u32x4;

// d_out layout (float32 values):
//   [0, NS)                      assignments (as float)
//   [NS, 2*NS)                   min_dists
//   [2*NS, 2*NS+KK)              leaf_counts
//   [2*NS+KK, +KK*DD)            leaf_sums
//   [2*NS+KK+KK*DD, +KK)         leaf_sum_sq_dist

__global__ void zero_buf(float* __restrict__ p, int n) {
    int i = blockIdx.x * 256 + threadIdx.x;
    if (i < n) p[i] = 0.f;
}

// ---- two-stage reduce over NCOPY copies of [256][66] partials ----
__global__ void reduce_ws1(float* __restrict__ ws) {
    int gid = blockIdx.x * 256 + threadIdx.x;
    if (gid >= NSTAT * RGROUPS) return;
    int g = gid / NSTAT, e = gid - g * NSTAT;
    const float* src = ws + (size_t)(g * RPER) * NSTAT + e;
    float s = 0.f;
    #pragma unroll 8
    for (int j = 0; j < RPER; ++j) s += src[(size_t)j * NSTAT];
    ws[(size_t)(g * RPER) * NSTAT + e] = s;
}

__global__ void reduce_ws2(const float* __restrict__ ws, float* __restrict__ o_stats) {
    int e = blockIdx.x * 256 + threadIdx.x;
    if (e >= NSTAT) return;
    float s = 0.f;
    #pragma unroll
    for (int g = 0; g < RGROUPS; ++g) s += ws[(size_t)(g * RPER) * NSTAT + e];
    int leaf = e / 66, c = e - leaf * 66;
    float* o_cnt = o_stats;
    float* o_sum = o_stats + KK;
    float* o_ssq = o_stats + KK + KK * DD;
    if (c < 64)       o_sum[leaf * 64 + c] = s;
    else if (c == 64) o_cnt[leaf] = s;
    else              o_ssq[leaf] = s;
}

// single-stage reduce (fallback paths only)
__global__ void reduce_ws(const float* __restrict__ ws, float* __restrict__ o_stats,
                          int ncopy) {
    int e = blockIdx.x * 256 + threadIdx.x;
    if (e >= NSTAT) return;
    float s = 0.f;
    #pragma unroll 8
    for (int j = 0; j < ncopy; ++j) s += ws[(size_t)j * NSTAT + e];
    int leaf = e / 66, c = e - leaf * 66;
    float* o_cnt = o_stats;
    float* o_sum = o_stats + KK;
    float* o_ssq = o_stats + KK + KK * DD;
    if (c < 64)       o_sum[leaf * 64 + c] = s;
    else if (c == 64) o_cnt[leaf] = s;
    else              o_ssq[leaf] = s;
}

__device__ inline unsigned short f2bf(float f) {
    unsigned u = __float_as_uint(f);
    u += 0x7FFFu + ((u >> 16) & 1u);          // round-to-nearest-even
    return (unsigned short)(u >> 16);
}
__device__ inline float bf2f(unsigned short b) {
    return __uint_as_float(((unsigned)b) << 16);
}

// ---------------- K1: MFMA argmin (verified r5-r8 core) ----------------
__global__ __launch_bounds__(512, 2)
void deepect_argmin(const float* __restrict__ mb, const float* __restrict__ ctr,
                    float* __restrict__ out) {
    __shared__ __align__(16) unsigned short s_ctr[KK][CPAD];
    __shared__ float s_csq[KK];

    const int tid  = threadIdx.x;
    const int lane = tid & 63;
    const int w    = tid >> 6;
    const int g    = lane >> 4;
    const int c16  = lane & 15;

    for (int idx = tid; idx < KK * 16; idx += 512) {
        int row = idx >> 4, f4 = idx & 15;
        float4 v = ((const float4*)(ctr + row * DD))[f4];
        ushort4 b;
        b.x = f2bf(v.x); b.y = f2bf(v.y); b.z = f2bf(v.z); b.w = f2bf(v.w);
        *(ushort4*)&s_ctr[row][f4 * 4] = b;
    }
    __syncthreads();

    if (tid < KK) {
        float acc = 0.f;
        #pragma unroll
        for (int j = 0; j < 16; ++j) {
            ushort4 b = *(ushort4*)&s_ctr[tid][j * 4];
            float x0 = bf2f(b.x), x1 = bf2f(b.y), x2 = bf2f(b.z), x3 = bf2f(b.w);
            acc += x0 * x0 + x1 * x1 + x2 * x2 + x3 * x3;
        }
        s_csq[tid] = acc;
    }
    __syncthreads();

    float csqh[16];
    #pragma unroll
    for (int t = 0; t < 16; ++t) csqh[t] = -0.5f * s_csq[t * 16 + c16];

    const int sbase = blockIdx.x * 256 + w * 32;

    bf16x8 afr[2][2];
    float  xsq_rt[2];
    #pragma unroll
    for (int rt = 0; rt < 2; ++rt) {
        float px = 0.f;
        #pragma unroll
        for (int ks = 0; ks < 2; ++ks) {
            const float* rp = mb + (size_t)(sbase + rt * 16 + c16) * DD + g * 8 + ks * 32;
            float4 a = ((const float4*)rp)[0];
            float4 b = ((const float4*)rp)[1];
            bf16x8 f;
            f[0] = (short)f2bf(a.x); f[1] = (short)f2bf(a.y);
            f[2] = (short)f2bf(a.z); f[3] = (short)f2bf(a.w);
            f[4] = (short)f2bf(b.x); f[5] = (short)f2bf(b.y);
            f[6] = (short)f2bf(b.z); f[7] = (short)f2bf(b.w);
            afr[rt][ks] = f;
            float q0 = bf2f(f2bf(a.x)), q1 = bf2f(f2bf(a.y)), q2 = bf2f(f2bf(a.z)), q3 = bf2f(f2bf(a.w));
            float q4 = bf2f(f2bf(b.x)), q5 = bf2f(f2bf(b.y)), q6 = bf2f(f2bf(b.z)), q7 = bf2f(f2bf(b.w));
            px += q0*q0 + q1*q1 + q2*q2 + q3*q3 + q4*q4 + q5*q5 + q6*q6 + q7*q7;
        }
        px += __shfl_xor(px, 16, 64);
        px += __shfl_xor(px, 32, 64);
        xsq_rt[rt] = px;
    }

    float bestv[2][4];
    int   besti[2][4];
    #pragma unroll
    for (int rt = 0; rt < 2; ++rt)
        #pragma unroll
        for (int r = 0; r < 4; ++r) { bestv[rt][r] = -FLT_MAX; besti[rt][r] = 0; }

    #pragma unroll
    for (int t = 0; t < 16; ++t) {
        bf16x8 b0 = *(bf16x8*)&s_ctr[t * 16 + c16][g * 8];
        bf16x8 b1 = *(bf16x8*)&s_ctr[t * 16 + c16][g * 8 + 32];
        const int colidx = t * 16 + c16;
        #pragma unroll
        for (int rt = 0; rt < 2; ++rt) {
            f32x4 acc;
            acc[0] = csqh[t]; acc[1] = csqh[t]; acc[2] = csqh[t]; acc[3] = csqh[t];
            acc = __builtin_amdgcn_mfma_f32_16x16x32_bf16(afr[rt][0], b0, acc, 0, 0, 0);
            acc = __builtin_amdgcn_mfma_f32_16x16x32_bf16(afr[rt][1], b1, acc, 0, 0, 0);
            #pragma unroll
            for (int r = 0; r < 4; ++r) {
                if (acc[r] > bestv[rt][r]) { bestv[rt][r] = acc[r]; besti[rt][r] = colidx; }
            }
        }
    }

    float* o_assign = out;
    float* o_mind   = out + NS;

    #pragma unroll
    for (int rt = 0; rt < 2; ++rt) {
        #pragma unroll
        for (int r = 0; r < 4; ++r) {
            float v  = bestv[rt][r];
            int   bi = besti[rt][r];
            #pragma unroll
            for (int off = 1; off < 16; off <<= 1) {
                float ov = __shfl_xor(v, off, 64);
                int   oi = __shfl_xor(bi, off, 64);
                if (ov > v || (ov == v && oi < bi)) { v = ov; bi = oi; }
            }
            int src = (lane & 48) | (g * 4 + r);
            float xq = __shfl(xsq_rt[rt], src, 64);
            float dsq = fmaxf(xq - 2.0f * v, 0.f);
            if (c16 == 0) {
                int s = sbase + rt * 16 + g * 4 + r;
                o_assign[s] = (float)bi;
                o_mind[s]   = sqrtf(dsq);
            }
        }
    }
}

// ---------------- K2: stats as one-hot GEMM (verified r7/r8 core) ----------------
__global__ __launch_bounds__(512, 2)
void deepect_stats_gemm(const float* __restrict__ mb, const float* __restrict__ out,
                        float* __restrict__ ws) {
    __shared__ __align__(16) unsigned short s_xt[80][XTS];   // 42.2 KB
    __shared__ int s_bi[256];

    const int tid  = threadIdx.x;
    const int lane = tid & 63;
    const int w    = tid >> 6;
    const int g    = lane >> 4;
    const int c16  = lane & 15;
    const int base = blockIdx.x * 256;

    unsigned* xtw = (unsigned*)s_xt;

    for (int i = tid; i < 14 * XTSW; i += 512) xtw[66 * XTSW + i] = 0u;

    {
        const int dh = tid >> 7, sp = tid & 127;
        const float* r0 = mb + (size_t)(base + 2 * sp) * DD + dh * 16;
        const float* r1 = r0 + DD;
        #pragma unroll
        for (int q = 0; q < 4; ++q) {
            float4 a = ((const float4*)r0)[q];
            float4 b = ((const float4*)r1)[q];
            const int row = dh * 16 + q * 4;
            xtw[(row + 0) * XTSW + sp] = (unsigned)f2bf(a.x) | ((unsigned)f2bf(b.x) << 16);
            xtw[(row + 1) * XTSW + sp] = (unsigned)f2bf(a.y) | ((unsigned)f2bf(b.y) << 16);
            xtw[(row + 2) * XTSW + sp] = (unsigned)f2bf(a.z) | ((unsigned)f2bf(b.z) << 16);
            xtw[(row + 3) * XTSW + sp] = (unsigned)f2bf(a.w) | ((unsigned)f2bf(b.w) << 16);
        }
    }
    if (tid < 128) {
        const int sp = tid;
        float m0 = out[NS + base + 2 * sp];
        float m1 = out[NS + base + 2 * sp + 1];
        xtw[64 * XTSW + sp] = 0x3F803F80u;
        xtw[65 * XTSW + sp] = (unsigned)f2bf(m0 * m0) | ((unsigned)f2bf(m1 * m1) << 16);
    }
    if (tid < 256) s_bi[tid] = (int)out[base + tid];
    __syncthreads();

    f32x4 acc[2][5];
    #pragma unroll
    for (int L = 0; L < 2; ++L)
        #pragma unroll
        for (int dt = 0; dt < 5; ++dt) {
            acc[L][dt][0] = 0.f; acc[L][dt][1] = 0.f;
            acc[L][dt][2] = 0.f; acc[L][dt][3] = 0.f;
        }

    const int ml0 = w * 16 + c16;
    const int ml1 = (w + 8) * 16 + c16;

    #pragma unroll
    for (int ks = 0; ks < 8; ++ks) {
        const int kb = ks * 32 + g * 8;
        int4 bl = *(int4*)&s_bi[kb];
        int4 bh = *(int4*)&s_bi[kb + 4];
        bf16x8 bfrag[5];
        #pragma unroll
        for (int dt = 0; dt < 5; ++dt)
            bfrag[dt] = *(bf16x8*)&s_xt[dt * 16 + c16][kb];

        const int b0 = bl.x, b1 = bl.y, b2 = bl.z, b3 = bl.w;
        const int b4 = bh.x, b5 = bh.y, b6 = bh.z, b7 = bh.w;
        u32x4 u0, u1;
        u0[0] = (b0 == ml0 ? 0x3F80u : 0u) | (b1 == ml0 ? 0x3F800000u : 0u);
        u0[1] = (b2 == ml0 ? 0x3F80u : 0u) | (b3 == ml0 ? 0x3F800000u : 0u);
        u0[2] = (b4 == ml0 ? 0x3F80u : 0u) | (b5 == ml0 ? 0x3F800000u : 0u);
        u0[3] = (b6 == ml0 ? 0x3F80u : 0u) | (b7 == ml0 ? 0x3F800000u : 0u);
        u1[0] = (b0 == ml1 ? 0x3F80u : 0u) | (b1 == ml1 ? 0x3F800000u : 0u);
        u1[1] = (b2 == ml1 ? 0x3F80u : 0u) | (b3 == ml1 ? 0x3F800000u : 0u);
        u1[2] = (b4 == ml1 ? 0x3F80u : 0u) | (b5 == ml1 ? 0x3F800000u : 0u);
        u1[3] = (b6 == ml1 ? 0x3F80u : 0u) | (b7 == ml1 ? 0x3F800000u : 0u);
        bf16x8 a0 = __builtin_bit_cast(bf16x8, u0);
        bf16x8 a1 = __builtin_bit_cast(bf16x8, u1);

        #pragma unroll
        for (int dt = 0; dt < 5; ++dt) {
            acc[0][dt] = __builtin_amdgcn_mfma_f32_16x16x32_bf16(a0, bfrag[dt], acc[0][dt], 0, 0, 0);
            acc[1][dt] = __builtin_amdgcn_mfma_f32_16x16x32_bf16(a1, bfrag[dt], acc[1][dt], 0, 0, 0);
        }
    }

    float* dst = ws + (size_t)blockIdx.x * NSTAT;
    #pragma unroll
    for (int L = 0; L < 2; ++L) {
        const int lt = (L == 0) ? w : (w + 8);
        #pragma unroll
        for (int dt = 0; dt < 5; ++dt) {
            const int col = dt * 16 + c16;
            #pragma unroll
            for (int r = 0; r < 4; ++r) {
                const int leaf = lt * 16 + g * 4 + r;
                if (col < 66) dst[leaf * 66 + col] = acc[L][dt][r];
            }
        }
    }
}

// ---------------- fallback: LDS-atomic stats (only if ws is too small) ----------------
__global__ __launch_bounds__(512)
void deepect_stats_atomic(const float* __restrict__ mb, const float* __restrict__ out,
                          float* __restrict__ wsdst, int ncopy, int mode) {
    __shared__ float s_cnt[KK];
    __shared__ float s_ssq[KK];
    __shared__ float s_sum[KK][65];

    const int tid = threadIdx.x;
    for (int idx = tid; idx < KK; idx += 512) { s_cnt[idx] = 0.f; s_ssq[idx] = 0.f; }
    for (int idx = tid; idx < KK * 65; idx += 512) ((float*)s_sum)[idx] = 0.f;
    __syncthreads();

    const int grp = tid >> 4;
    const int d4  = tid & 15;
    const int ibase = blockIdx.x * 512 + grp * 16;

    for (int s = 0; s < 16; ++s) {
        const int i = ibase + s;
        const int bi = (int)out[i];
        float4 v = ((const float4*)(mb + (size_t)i * DD))[d4];
        atomicAdd(&s_sum[bi][d4 * 4 + 0], v.x);
        atomicAdd(&s_sum[bi][d4 * 4 + 1], v.y);
        atomicAdd(&s_sum[bi][d4 * 4 + 2], v.z);
        atomicAdd(&s_sum[bi][d4 * 4 + 3], v.w);
        if (d4 == 0) {
            const float md = out[NS + i];
            atomicAdd(&s_cnt[bi], 1.0f);
            atomicAdd(&s_ssq[bi], md * md);
        }
    }
    __syncthreads();

    if (mode == 0) {
        const size_t cb = (size_t)(blockIdx.x & (ncopy - 1)) * NSTAT;
        for (int idx = tid; idx < KK; idx += 512) {
            atomicAdd(&wsdst[cb + idx * 66 + 64], s_cnt[idx]);
            atomicAdd(&wsdst[cb + idx * 66 + 65], s_ssq[idx]);
        }
        for (int idx = tid; idx < KK * DD; idx += 512)
            atomicAdd(&wsdst[cb + (idx >> 6) * 66 + (idx & 63)], s_sum[idx >> 6][idx & 63]);
    } else {
        for (int idx = tid; idx < KK; idx += 512) {
            atomicAdd(&wsdst[idx], s_cnt[idx]);
            atomicAdd(&wsdst[KK + KK * DD + idx], s_ssq[idx]);
        }
        for (int idx = tid; idx < KK * DD; idx += 512)
            atomicAdd(&wsdst[KK + idx], s_sum[idx >> 6][idx & 63]);
    }
}

extern "C" void kernel_launch(void* const* d_in, const int* in_sizes, int n_in,
                              void* d_out, int out_size, void* d_ws, size_t ws_size,
                              hipStream_t stream) {
    const float* mb  = (const float*)d_in[0];
    const float* ctr = (const float*)d_in[1];
    float* out = (float*)d_out;
    float* o_stats = out + 2 * NS;
    float* ws = (float*)d_ws;

    hipLaunchKernelGGL(deepect_argmin, dim3(NS / 256), dim3(512), 0, stream,
                       mb, ctr, out);

    const size_t need512 = (size_t)NCOPY * NSTAT * sizeof(float);  // 34.6 MB
    const size_t need64  = (size_t)64    * NSTAT * sizeof(float);  //  4.3 MB

    if (ws_size >= need512) {
        // fast path: one-hot GEMM stats + two-stage parallel reduce, no atomics
        hipLaunchKernelGGL(deepect_stats_gemm, dim3(NS / 256), dim3(512), 0, stream,
                           mb, out, ws);
        hipLaunchKernelGGL(reduce_ws1, dim3((NSTAT * RGROUPS + 255) / 256), dim3(256),
                           0, stream, ws);
        hipLaunchKernelGGL(reduce_ws2, dim3((NSTAT + 255) / 256), dim3(256), 0, stream,
                           ws, o_stats);
    } else if (ws_size >= need64) {
        hipLaunchKernelGGL(zero_buf, dim3((64 * NSTAT + 255) / 256), dim3(256), 0,
                           stream, ws, 64 * NSTAT);
        hipLaunchKernelGGL(deepect_stats_atomic, dim3(NS / 512), dim3(512), 0, stream,
                           mb, out, ws, 64, 0);
        hipLaunchKernelGGL(reduce_ws, dim3((NSTAT + 255) / 256), dim3(256), 0, stream,
                           ws, o_stats, 64);
    } else {
        hipLaunchKernelGGL(zero_buf, dim3((NSTAT + 255) / 256), dim3(256), 0, stream,
                           o_stats, NSTAT);
        hipLaunchKernelGGL(deepect_stats_atomic, dim3(NS / 512), dim3(512), 0, stream,
                           mb, out, o_stats, 1, 1);
    }
}